// Round 1
// baseline (248.665 us; speedup 1.0000x reference)
//
#include <hip/hip_runtime.h>
#include <math.h>

#define NPART 62
#define M 512
#define D 256
#define KSAMP 8
#define MARGIN 0.2f
#define TA 32            // anchors per block
#define BK 16            // k-chunk
#define NCHUNK (D / BK)  // 16
#define NT 256

// Block: part n (blockIdx.y), anchors [a0, a0+32) (blockIdx.x*32).
// Wave w owns anchor rows w*8..w*8+8; lane owns columns j = lane + 64*c.
__global__ __launch_bounds__(NT) void triplet_main(
    const float* __restrict__ feat, const int* __restrict__ label,
    float* __restrict__ ws)
{
    __shared__ float Bs[BK * M];   // [kk][j], 32 KB
    __shared__ float x2s[M];       // squared norms of all 512 rows
    __shared__ int   labs[M];      // labels (row 0)

    const int t    = threadIdx.x;
    const int lane = t & 63;
    const int w    = t >> 6;
    const int n    = blockIdx.y;
    const int a0   = blockIdx.x * TA;
    const float* F = feat + (size_t)n * M * D;

    labs[t]       = label[t];
    labs[t + 256] = label[t + 256];

    float acc[8][8];
#pragma unroll
    for (int r = 0; r < 8; ++r)
#pragma unroll
        for (int c = 0; c < 8; ++c) acc[r][c] = 0.f;

    float x2p0 = 0.f, x2p1 = 0.f;

    for (int kc = 0; kc < NCHUNK; ++kc) {
        const int k0 = kc * BK;
        __syncthreads();
        // stage: 512 rows x 16 k-floats, coalesced float4 loads
#pragma unroll
        for (int it = 0; it < 8; ++it) {
            const int idx = t + NT * it;
            const int j   = idx >> 2;
            const int k4  = idx & 3;
            const float4 v = *reinterpret_cast<const float4*>(
                F + (size_t)j * D + k0 + k4 * 4);
            Bs[(k4 * 4 + 0) * M + j] = v.x;
            Bs[(k4 * 4 + 1) * M + j] = v.y;
            Bs[(k4 * 4 + 2) * M + j] = v.z;
            Bs[(k4 * 4 + 3) * M + j] = v.w;
        }
        __syncthreads();
        // squared-norm partials: thread t owns j=t and j=t+256 (deterministic)
#pragma unroll
        for (int kk = 0; kk < BK; ++kk) {
            const float v0 = Bs[kk * M + t];
            const float v1 = Bs[kk * M + t + 256];
            x2p0 += v0 * v0;
            x2p1 += v1 * v1;
        }
        // 8x8 register-blocked fp32 outer product
#pragma unroll 4
        for (int kk = 0; kk < BK; ++kk) {
            float a_frag[8], b_frag[8];
#pragma unroll
            for (int r = 0; r < 8; ++r)   // wave-uniform address -> broadcast
                a_frag[r] = Bs[kk * M + a0 + w * 8 + r];
#pragma unroll
            for (int c = 0; c < 8; ++c)   // lane-consecutive -> 2-way (free)
                b_frag[c] = Bs[kk * M + lane + 64 * c];
#pragma unroll
            for (int r = 0; r < 8; ++r)
#pragma unroll
                for (int c = 0; c < 8; ++c)
                    acc[r][c] += a_frag[r] * b_frag[c];
        }
    }
    x2s[t]       = x2p0;
    x2s[t + 256] = x2p1;
    __syncthreads();

    // hoist per-lane column data (j = lane + 64c is fixed per lane)
    int   labj[8];
    float x2j[8];
#pragma unroll
    for (int c = 0; c < 8; ++c) {
        labj[c] = labs[lane + 64 * c];
        x2j[c]  = x2s[lane + 64 * c];
    }

    float fullsum = 0.f, fullcnt = 0.f, distsum = 0.f, hardsum = 0.f;

#pragma unroll // full unroll: acc[r][..] must stay statically indexed
    for (int r = 0; r < 8; ++r) {
        const int   gi   = a0 + w * 8 + r;
        const float x2i  = x2s[gi];
        const int   labi = labs[gi];

        float d[8];
#pragma unroll
        for (int c = 0; c < 8; ++c) {
            const float d2 = x2i + x2j[c] - 2.f * acc[r][c];
            d[c] = (d2 > 0.f) ? sqrtf(d2) : 0.f;
            distsum += d[c];
        }

        // positive block: labels are K_SAMP-blocks -> pos j in [8*labi, 8*labi+8)
        const int pb   = labi * KSAMP;
        const int cpos = pb >> 6;            // block of 8 never crosses a c-boundary
        float dv = d[0];
#pragma unroll
        for (int c = 1; c < 8; ++c) dv = (cpos == c) ? d[c] : dv;  // static select
        float hp[8];
#pragma unroll
        for (int p = 0; p < 8; ++p) hp[p] = __shfl(dv, (pb & 63) + p);
        float hpmax = hp[0];
#pragma unroll
        for (int p = 1; p < 8; ++p) hpmax = fmaxf(hpmax, hp[p]);

        float hnmin = 3.0e38f;
#pragma unroll
        for (int c = 0; c < 8; ++c) {
            if (labj[c] != labi) {
                const float dc = d[c];
                hnmin = fminf(hnmin, dc);
#pragma unroll
                for (int p = 0; p < 8; ++p) {
                    const float v = MARGIN + hp[p] - dc;
                    fullsum += fmaxf(v, 0.f);
                    fullcnt += (v > 0.f) ? 1.f : 0.f;
                }
            }
        }
#pragma unroll
        for (int o = 32; o > 0; o >>= 1)
            hnmin = fminf(hnmin, __shfl_xor(hnmin, o));
        if (lane == 0) {
            const float h = MARGIN + hpmax - hnmin;
            hardsum += (h > 0.f) ? h : 0.f;
        }
    }

#pragma unroll
    for (int o = 32; o > 0; o >>= 1) {
        fullsum += __shfl_xor(fullsum, o);
        fullcnt += __shfl_xor(fullcnt, o);
        distsum += __shfl_xor(distsum, o);
    }
    if (lane == 0) {
        atomicAdd(&ws[n * 4 + 0], fullsum);
        atomicAdd(&ws[n * 4 + 1], fullcnt);
        atomicAdd(&ws[n * 4 + 2], hardsum);
        atomicAdd(&ws[n * 4 + 3], distsum);
    }
}

__global__ void triplet_finalize(const float* __restrict__ ws,
                                 float* __restrict__ out)
{
    const int i = threadIdx.x;
    if (i < NPART) {
        const float fs = ws[i * 4 + 0];
        const float fc = ws[i * 4 + 1];
        const float hs = ws[i * 4 + 2];
        const float ds = ws[i * 4 + 3];
        out[i]             = (fc == 0.f) ? 0.f : fs / fmaxf(fc, 1.f);
        out[NPART + i]     = hs / (float)M;
        out[2 * NPART + i] = ds / ((float)M * (float)M);
        out[3 * NPART + i] = fc;
    }
}

extern "C" void kernel_launch(void* const* d_in, const int* in_sizes, int n_in,
                              void* d_out, int out_size, void* d_ws, size_t ws_size,
                              hipStream_t stream)
{
    (void)in_sizes; (void)n_in; (void)out_size; (void)ws_size;
    const float* feat  = (const float*)d_in[0];
    const int*   label = (const int*)d_in[1];
    float*       ws    = (float*)d_ws;

    hipMemsetAsync(ws, 0, NPART * 4 * sizeof(float), stream);
    dim3 grid(M / TA, NPART);
    triplet_main<<<grid, NT, 0, stream>>>(feat, label, ws);
    triplet_finalize<<<1, 64, 0, stream>>>(ws, (float*)d_out);
}

// Round 2
// 84.678 us; speedup vs baseline: 2.9366x; 2.9366x over previous
//
#include <hip/hip_runtime.h>
#include <math.h>

#define NPART 62
#define M 512
#define D 256
#define KSAMP 8
#define MARGIN 0.2f
#define NT 256
#define BKK 32           // k per step
#define NKSTEP (D / BKK) // 8

typedef __attribute__((ext_vector_type(8))) short bf16x8;
typedef __attribute__((ext_vector_type(4))) float f32x4;

__device__ __forceinline__ unsigned bf16_rne(float f) {
    unsigned u = __builtin_bit_cast(unsigned, f);
    return (u + 0x7FFFu + ((u >> 16) & 1u)) >> 16;
}

// Block: part n, anchor rows [R0, R0+64) x all 512 cols of the gram.
// 4 waves; wave w owns cols [128w, 128w+128). MFMA 16x16x32 bf16, split-hi/lo.
__global__ __launch_bounds__(NT, 2) void triplet_main(
    const float* __restrict__ feat, const int* __restrict__ label,
    float* __restrict__ ws)
{
    __shared__ bf16x8 hiS[M * 4];            // [row][group], 32 KB, XOR-swizzled
    __shared__ bf16x8 loS[M * 4];            // 32 KB
    __shared__ float  x2s[M];                // 2 KB
    __shared__ int    labsS[M];              // 2 KB
    __shared__ __align__(16) float hpL[64 * 8]; // 2 KB: hp per local row
    __shared__ float  hnw[64 * 4];           // 1 KB: per-row per-wave hn-min

    const int t    = threadIdx.x;
    const int lane = t & 63;
    const int w    = t >> 6;
    const int lr   = lane & 15;
    const int h    = lane >> 4;

    // XCD swizzle: dispatch d -> slot s so each part's 8 blocks share an XCD.
    const int d_ = blockIdx.x;
    const int s  = (d_ & 7) * 62 + (d_ >> 3);   // bijective on [0,496)
    const int n  = s >> 3;                      // part
    const int bx = s & 7;                       // row chunk
    const int R0 = bx * 64;
    const float* F = feat + (size_t)n * (M * D);

    labsS[t]       = label[n * M + t];
    labsS[t + 256] = label[n * M + t + 256];

    float x2q[8];
#pragma unroll
    for (int i = 0; i < 8; ++i) x2q[i] = 0.f;

    f32x4 acc[4][8];
    const f32x4 zero4 = {0.f, 0.f, 0.f, 0.f};
#pragma unroll
    for (int a = 0; a < 4; ++a)
#pragma unroll
        for (int b = 0; b < 8; ++b) acc[a][b] = zero4;

    // fragment LDS indices (constant across k-steps)
    int aIdx[4], bIdx[8];
#pragma unroll
    for (int rb = 0; rb < 4; ++rb) {
        const int row = R0 + rb * 16 + lr;
        aIdx[rb] = row * 4 + (h ^ ((row >> 1) & 3));
    }
#pragma unroll
    for (int cb = 0; cb < 8; ++cb) {
        const int row = w * 128 + cb * 16 + lr;
        bIdx[cb] = row * 4 + (h ^ ((row >> 1) & 3));
    }
    // staging assignment: idx = t + 256*it -> row = idx>>2, quarter qq = t&3
    int sRowA[8], sDstA[8];
#pragma unroll
    for (int it = 0; it < 8; ++it) {
        const int idx = t + 256 * it;
        const int row = idx >> 2, qq = idx & 3;
        sRowA[it] = row;
        sDstA[it] = row * 4 + (qq ^ ((row >> 1) & 3));
    }
    const int qoff = (t & 3) * 8;

    for (int kc = 0; kc < NKSTEP; ++kc) {
        const int k0 = kc * BKK;
        __syncthreads();
#pragma unroll
        for (int it = 0; it < 8; ++it) {
            const float* src = F + (size_t)sRowA[it] * D + k0 + qoff;
            const float4 v0 = *(const float4*)src;
            const float4 v1 = *(const float4*)(src + 4);
            const float v[8] = {v0.x, v0.y, v0.z, v0.w, v1.x, v1.y, v1.z, v1.w};
            bf16x8 h8, l8;
#pragma unroll
            for (int e = 0; e < 8; ++e) {
                const float f = v[e];
                const unsigned hr = bf16_rne(f);
                const float hf = __builtin_bit_cast(float, hr << 16);
                h8[e] = (short)hr;
                l8[e] = (short)bf16_rne(f - hf);
                x2q[it] += f * f;
            }
            hiS[sDstA[it]] = h8;
            loS[sDstA[it]] = l8;
        }
        __syncthreads();

        bf16x8 ah[4], al[4];
#pragma unroll
        for (int rb = 0; rb < 4; ++rb) { ah[rb] = hiS[aIdx[rb]]; al[rb] = loS[aIdx[rb]]; }
#pragma unroll
        for (int cb = 0; cb < 8; ++cb) {
            const bf16x8 bh = hiS[bIdx[cb]];
            const bf16x8 bl = loS[bIdx[cb]];
#pragma unroll
            for (int rb = 0; rb < 4; ++rb) {
                acc[rb][cb] = __builtin_amdgcn_mfma_f32_16x16x32_bf16(ah[rb], bh, acc[rb][cb], 0, 0, 0);
                acc[rb][cb] = __builtin_amdgcn_mfma_f32_16x16x32_bf16(al[rb], bh, acc[rb][cb], 0, 0, 0);
                acc[rb][cb] = __builtin_amdgcn_mfma_f32_16x16x32_bf16(ah[rb], bl, acc[rb][cb], 0, 0, 0);
            }
        }
    }

    // combine x2 quarters (threads t, t^1, t^2, t^3 share a row)
#pragma unroll
    for (int it = 0; it < 8; ++it) {
        float x = x2q[it];
        x += __shfl_xor(x, 1);
        x += __shfl_xor(x, 2);
        if ((t & 3) == 0) x2s[sRowA[it]] = x;
    }
    __syncthreads();

    // ---- epilogue: distances + losses on the MFMA C layout ----
    // acc[rb][cb][q] = G[R0 + rb*16 + h*4 + q][w*128 + cb*16 + lr]
    float x2r[4][4];
    int   labr_[4][4];
#pragma unroll
    for (int rb = 0; rb < 4; ++rb)
#pragma unroll
        for (int q = 0; q < 4; ++q) {
            const int gi = R0 + rb * 16 + h * 4 + q;
            x2r[rb][q]  = x2s[gi];
            labr_[rb][q] = labsS[gi];
        }
    float x2c[8];
    int   labc[8];
#pragma unroll
    for (int cb = 0; cb < 8; ++cb) {
        const int cj = w * 128 + cb * 16 + lr;
        x2c[cb] = x2s[cj];
        labc[cb] = labsS[cj];
    }

    float mdsum = 0.f;
#pragma unroll
    for (int rb = 0; rb < 4; ++rb)
#pragma unroll
        for (int cb = 0; cb < 8; ++cb) {
            f32x4 a = acc[rb][cb];
#pragma unroll
            for (int q = 0; q < 4; ++q) {
                const float d2 = x2r[rb][q] + x2c[cb] - 2.f * a[q];
                const float dd = (d2 > 0.f) ? sqrtf(d2) : 0.f;
                a[q] = dd;
                mdsum += dd;
                if (labc[cb] == labr_[rb][q])   // pos entry: exactly one writer
                    hpL[(rb * 16 + h * 4 + q) * 8 + (lane & 7)] = dd;
            }
            acc[rb][cb] = a;
        }
    __syncthreads();

    float fsum = 0.f, fcnt = 0.f;
#pragma unroll
    for (int rb = 0; rb < 4; ++rb)
#pragma unroll
        for (int q = 0; q < 4; ++q) {
            const int rl   = rb * 16 + h * 4 + q;
            const int labi = labr_[rb][q];
            const float4 hp0 = *(const float4*)&hpL[rl * 8];
            const float4 hp1 = *(const float4*)&hpL[rl * 8 + 4];
            const float mhp[8] = {MARGIN + hp0.x, MARGIN + hp0.y, MARGIN + hp0.z, MARGIN + hp0.w,
                                  MARGIN + hp1.x, MARGIN + hp1.y, MARGIN + hp1.z, MARGIN + hp1.w};
            float hn = 3.0e38f;
#pragma unroll
            for (int cb = 0; cb < 8; ++cb) {
                if (labc[cb] != labi) {
                    const float dd = acc[rb][cb][q];
                    hn = fminf(hn, dd);
#pragma unroll
                    for (int p = 0; p < 8; ++p) {
                        const float vv = mhp[p] - dd;
                        fsum += fmaxf(vv, 0.f);
                        fcnt += (vv > 0.f) ? 1.f : 0.f;
                    }
                }
            }
            hn = fminf(hn, __shfl_xor(hn, 1));
            hn = fminf(hn, __shfl_xor(hn, 2));
            hn = fminf(hn, __shfl_xor(hn, 4));
            hn = fminf(hn, __shfl_xor(hn, 8));
            if (lr == 0) hnw[rl * 4 + w] = hn;
        }

#pragma unroll
    for (int o = 32; o > 0; o >>= 1) {
        fsum  += __shfl_xor(fsum, o);
        fcnt  += __shfl_xor(fcnt, o);
        mdsum += __shfl_xor(mdsum, o);
    }
    if (lane == 0) {
        atomicAdd(&ws[n * 4 + 0], fsum);
        atomicAdd(&ws[n * 4 + 1], fcnt);
        atomicAdd(&ws[n * 4 + 3], mdsum);
    }
    __syncthreads();

    if (t < 64) {
        const float hn = fminf(fminf(hnw[t * 4 + 0], hnw[t * 4 + 1]),
                               fminf(hnw[t * 4 + 2], hnw[t * 4 + 3]));
        float hm = hpL[t * 8];
#pragma unroll
        for (int p = 1; p < 8; ++p) hm = fmaxf(hm, hpL[t * 8 + p]);
        float hd = MARGIN + hm - hn;
        hd = (hd > 0.f) ? hd : 0.f;
#pragma unroll
        for (int o = 32; o > 0; o >>= 1) hd += __shfl_xor(hd, o);
        if (t == 0) atomicAdd(&ws[n * 4 + 2], hd);
    }
}

__global__ void triplet_finalize(const float* __restrict__ ws,
                                 float* __restrict__ out)
{
    const int i = threadIdx.x;
    if (i < NPART) {
        const float fs = ws[i * 4 + 0];
        const float fc = ws[i * 4 + 1];
        const float hs = ws[i * 4 + 2];
        const float ds = ws[i * 4 + 3];
        out[i]             = (fc == 0.f) ? 0.f : fs / fmaxf(fc, 1.f);
        out[NPART + i]     = hs / (float)M;
        out[2 * NPART + i] = ds / ((float)M * (float)M);
        out[3 * NPART + i] = fc;
    }
}

extern "C" void kernel_launch(void* const* d_in, const int* in_sizes, int n_in,
                              void* d_out, int out_size, void* d_ws, size_t ws_size,
                              hipStream_t stream)
{
    (void)in_sizes; (void)n_in; (void)out_size; (void)ws_size;
    const float* feat  = (const float*)d_in[0];
    const int*   label = (const int*)d_in[1];
    float*       ws    = (float*)d_ws;

    hipMemsetAsync(ws, 0, NPART * 4 * sizeof(float), stream);
    triplet_main<<<dim3(NPART * 8), NT, 0, stream>>>(feat, label, ws);
    triplet_finalize<<<1, 64, 0, stream>>>(ws, (float*)d_out);
}